// Round 8
// baseline (918.991 us; speedup 1.0000x reference)
//
#include <hip/hip_runtime.h>

#define N_ROWS  65536
#define K_CB    4096
#define D_MODEL 512
#define TAU     0.35f
#define CAPA    8192
#define CAPB    8192

typedef __attribute__((ext_vector_type(8))) _Float16 f16x8;
typedef __attribute__((ext_vector_type(4))) float f32x4;
typedef unsigned int        u32;
typedef unsigned long long  u64;

__device__ __forceinline__ void load_lds16(const void* g, void* l) {
    __builtin_amdgcn_global_load_lds(
        (const __attribute__((address_space(1))) u32*)g,
        (__attribute__((address_space(3))) u32*)l, 16, 0, 0);
}

// non-temporal variant (aux=2 -> slc/nt): for streamed, zero-reuse sources
__device__ __forceinline__ void load_lds16_nt(const void* g, void* l) {
    __builtin_amdgcn_global_load_lds(
        (const __attribute__((address_space(1))) u32*)g,
        (__attribute__((address_space(3))) u32*)l, 16, 0, 2);
}

__device__ __forceinline__ u32 ordf(float f) {
    u32 u = __float_as_uint(f);
    return (u >> 31) ? ~u : (u | 0x80000000u);
}

// ---------------- z -> fp16 ----------------
__global__ __launch_bounds__(256) void convert_z(const float* __restrict__ z,
                                                 _Float16* __restrict__ zh) {
    size_t i = ((size_t)blockIdx.x * 256 + threadIdx.x) * 8;
    float4 a = *(const float4*)(z + i);
    float4 b = *(const float4*)(z + i + 4);
    f16x8 o;
    o[0] = (_Float16)a.x; o[1] = (_Float16)a.y; o[2] = (_Float16)a.z; o[3] = (_Float16)a.w;
    o[4] = (_Float16)b.x; o[5] = (_Float16)b.y; o[6] = (_Float16)b.z; o[7] = (_Float16)b.w;
    *(f16x8*)(zh + i) = o;
}

// ---------------- w -> fp16 + wsq (fp32, validated chain) + zero counters ----------------
__global__ __launch_bounds__(256) void convert_w(const float* __restrict__ w,
                                                 _Float16* __restrict__ wh,
                                                 float* __restrict__ wsq,
                                                 int* __restrict__ counterA,
                                                 int* __restrict__ counterB) {
    if (blockIdx.x == 0 && threadIdx.x == 0) { *counterA = 0; *counterB = 0; }
    int k    = blockIdx.x * 4 + (threadIdx.x >> 6);
    int lane = threadIdx.x & 63;
    const float4* row = (const float4*)(w + (size_t)k * D_MODEL);
    float s = 0.f;
    #pragma unroll
    for (int c = 0; c < 2; ++c) {
        float4 v = row[lane + 64 * c];
        s += v.x * v.x + v.y * v.y + v.z * v.z + v.w * v.w;
        _Float16* o = wh + (size_t)k * D_MODEL + (lane + 64 * c) * 4;
        o[0] = (_Float16)v.x; o[1] = (_Float16)v.y; o[2] = (_Float16)v.z; o[3] = (_Float16)v.w;
    }
    #pragma unroll
    for (int m = 32; m; m >>= 1) s += __shfl_xor(s, m, 64);
    if (lane == 0) wsq[k] = s;
}

// ---------------- fused fp16-MFMA GEMM + top-3 argmin + classify + gather ----------------
// EXACT r4 structure (638us verified): BM=64, 4 waves x (16 rows x 128 cols), BK=64,
// double-buffered LDS, flattened 256-chunk pipeline, counted vmcnt(6) + raw barriers.
// r7 changes: zh staged with NT hint (keep wh L2-resident); setprio around MFMA.
__global__ __launch_bounds__(256, 3) void gemm_argmin(
    const _Float16* __restrict__ zh, const _Float16* __restrict__ wh,
    const float* __restrict__ w, const float* __restrict__ wsq,
    float* __restrict__ out_idx, float* __restrict__ out_q,
    int4* __restrict__ listA, int* __restrict__ listB, u64* __restrict__ slots,
    int* __restrict__ counterA, int* __restrict__ counterB) {
    __shared__ _Float16 As[2][64 * 64];     // 2 x 8KB
    __shared__ _Float16 Bs[2][128 * 64];    // 2 x 16KB
    __shared__ int idx_s[64];

    const int tid  = threadIdx.x;
    const int lane = tid & 63;
    const int wv   = tid >> 6;
    const int m0   = blockIdx.x * 64;
    const int l15  = lane & 15;
    const int g    = lane >> 4;

    const int srow = lane >> 3;            // row within an 8-row / 1KB chunk
    const int scol = (lane & 7) ^ srow;    // pre-swizzled source 16B-column

    float v1[4], v2[4], v3[4]; int i1[4], i2[4];
    #pragma unroll
    for (int i = 0; i < 4; ++i) { v1[i] = 3.4e38f; v2[i] = 3.4e38f; v3[i] = 3.4e38f; i1[i] = 0; i2[i] = 0; }

    // stage chunk (kts, d0s) into buffer b: 6 global_load_lds per wave
    auto STAGE = [&](int kts, int d0s, int b) {
        const int chA = wv << 1;
        const _Float16* as = zh + (size_t)(m0 + (chA << 3) + srow) * D_MODEL + d0s + scol * 8;
        load_lds16_nt(as,                       &As[b][chA << 9]);          // NT: z streamed once
        load_lds16_nt(as + (size_t)8 * D_MODEL, &As[b][(chA + 1) << 9]);
        const int chB = wv << 2;
        const _Float16* bs = wh + (size_t)(kts * 128 + (chB << 3) + srow) * D_MODEL + d0s + scol * 8;
        #pragma unroll
        for (int q = 0; q < 4; ++q)
            load_lds16(bs + (size_t)(q * 8) * D_MODEL, &Bs[b][(chB + q) << 9]);  // cached: reused
    };

    STAGE(0, 0, 0);                                    // prologue: chunk 0 -> buf 0

    for (int kt = 0; kt < 32; ++kt) {
        f32x4 acc[8];
        float wq[8];
        #pragma unroll
        for (int dc = 0; dc < 8; ++dc) {
            const int cur = dc & 1;
            // ---- issue next chunk's stage (skip only after the very last chunk)
            if (dc < 7) {
                STAGE(kt, (dc + 1) << 6, cur ^ 1);
                asm volatile("s_waitcnt vmcnt(6)" ::: "memory");
            } else if (kt < 31) {
                STAGE(kt + 1, 0, cur ^ 1);
                asm volatile("s_waitcnt vmcnt(6)" ::: "memory");
            } else {
                asm volatile("s_waitcnt vmcnt(0)" ::: "memory");
            }
            __builtin_amdgcn_s_barrier();              // current chunk visible to all waves
            __builtin_amdgcn_sched_barrier(0);

            if (dc == 0) {
                #pragma unroll
                for (int n = 0; n < 8; ++n) {
                    acc[n] = (f32x4){0.f, 0.f, 0.f, 0.f};
                    wq[n] = wsq[(kt << 7) + (n << 4) + l15];
                }
            }

            // ---- compute: wave tile 16 rows x 128 cols, 16 MFMA
            __builtin_amdgcn_s_setprio(1);
            #pragma unroll
            for (int h = 0; h < 2; ++h) {
                const int colq = (h << 2) + g;         // 16B-col unit (0..7)
                const int ar = (wv << 4) + l15;
                f16x8 af = *(const f16x8*)&As[cur][(ar << 6) + ((colq ^ (ar & 7)) << 3)];
                #pragma unroll
                for (int n = 0; n < 8; ++n) {
                    const int br = (n << 4) + l15;
                    f16x8 bv = *(const f16x8*)&Bs[cur][(br << 6) + ((colq ^ (br & 7)) << 3)];
                    acc[n] = __builtin_amdgcn_mfma_f32_16x16x32_f16(af, bv, acc[n], 0, 0, 0);
                }
            }
            __builtin_amdgcn_s_setprio(0);

            // ---- kt epilogue: registers only (wq preloaded)
            if (dc == 7) {
                #pragma unroll
                for (int n = 0; n < 8; ++n) {
                    int k = (kt << 7) + (n << 4) + l15;
                    #pragma unroll
                    for (int r = 0; r < 4; ++r) {
                        float s = fmaf(-2.f, acc[n][r], wq[n]);
                        if (s < v3[r]) {
                            if (s < v1[r]) {
                                v3[r] = v2[r]; v2[r] = v1[r]; i2[r] = i1[r];
                                v1[r] = s; i1[r] = k;
                            } else if (s < v2[r]) {
                                v3[r] = v2[r]; v2[r] = s; i2[r] = k;
                            } else v3[r] = s;
                        }
                    }
                }
            }
            __builtin_amdgcn_sched_barrier(0);
            __builtin_amdgcn_s_barrier();              // all waves done reading buf[cur]
        }
    }

    // merge sorted-3 lists across the 16 column-lanes (lex on (value, idx))
    #pragma unroll
    for (int rs = 0; rs < 4; ++rs) {
        float a1 = v1[rs], a2 = v2[rs], a3 = v3[rs];
        int   j1 = i1[rs], j2 = i2[rs];
        #pragma unroll
        for (int off = 1; off < 16; off <<= 1) {
            float b1 = __shfl_xor(a1, off);
            float b2 = __shfl_xor(a2, off);
            float b3 = __shfl_xor(a3, off);
            int   k1 = __shfl_xor(j1, off);
            int   k2 = __shfl_xor(j2, off);
            bool l1 = (b1 < a1) || (b1 == a1 && k1 < j1);
            bool l2 = (b1 < a2) || (b1 == a2 && k1 < j2);
            bool l3 = (b1 < a3);
            if (l1)      { a3 = a2; a2 = a1; j2 = j1; a1 = b1; j1 = k1; }
            else if (l2) { a3 = a2; a2 = b1; j2 = k1; }
            else if (l3) { a3 = b1; }
            bool m2 = (b2 < a2) || (b2 == a2 && k2 < j2);
            bool m3 = (b2 < a3);
            if (m2)      { a3 = a2; a2 = b2; j2 = k2; }
            else if (m3) { a3 = b2; }
            a3 = fminf(a3, b3);
        }
        if (l15 == 0) {
            int rl = (wv << 4) + (g << 2) + rs;
            int row = m0 + rl;
            out_idx[row] = (float)j1;
            idx_s[rl] = j1;
            float lim = a1 + TAU;
            if (a3 <= lim) {                       // >=3 candidates: full exact scan
                int p = atomicAdd(counterB, 1);
                if (p < CAPB) { listB[p] = row; slots[p] = ~0ull; }
            } else if (a2 <= lim) {                // exactly 2 candidates: pair verify
                int p = atomicAdd(counterA, 1);
                if (p < CAPA) listA[p] = make_int4(row, j1, j2, 0);
                else {
                    int q = atomicAdd(counterB, 1);
                    if (q < CAPB) { listB[q] = row; slots[q] = ~0ull; }
                }
            }
        }
    }
    __syncthreads();

    // gather quantized rows with idx1 (fallback kernels overwrite their rows)
    const float4* w4 = (const float4*)w;
    float4* o4 = (float4*)out_q;
    for (int c = tid; c < 64 * 128; c += 256) {
        int r = c >> 7, cc = c & 127;
        o4[(size_t)(m0 + r) * 128 + cc] = w4[(size_t)idx_s[r] * 128 + cc];
    }
}

// ---------------- exact fp32 pair-verify (one lane per ambiguous row) ----------------
__global__ __launch_bounds__(256) void verify_pairs(
    const float* __restrict__ z, const float* __restrict__ w,
    const float* __restrict__ wsq, const int4* __restrict__ listA,
    const int* __restrict__ counterA,
    float* __restrict__ out_idx, float* __restrict__ out_q) {
    int cA = *counterA; if (cA > CAPA) cA = CAPA;
    for (int e = blockIdx.x * 256 + threadIdx.x; e < cA; e += gridDim.x * 256) {
        int4 ent = listA[e];
        const float4* zr = (const float4*)(z + (size_t)ent.x * D_MODEL);
        const float4* wa = (const float4*)(w + (size_t)ent.y * D_MODEL);
        const float4* wb = (const float4*)(w + (size_t)ent.z * D_MODEL);
        float d1 = 0.f, d2 = 0.f;
        #pragma unroll 8
        for (int c = 0; c < 128; ++c) {
            float4 zv = zr[c];
            float4 a  = wa[c];
            float4 b  = wb[c];
            d1 = fmaf(zv.x, a.x, d1); d1 = fmaf(zv.y, a.y, d1);
            d1 = fmaf(zv.z, a.z, d1); d1 = fmaf(zv.w, a.w, d1);
            d2 = fmaf(zv.x, b.x, d2); d2 = fmaf(zv.y, b.y, d2);
            d2 = fmaf(zv.z, b.z, d2); d2 = fmaf(zv.w, b.w, d2);
        }
        float s1 = fmaf(-2.f, d1, wsq[ent.y]);
        float s2 = fmaf(-2.f, d2, wsq[ent.z]);
        int win = (s2 < s1 || (s2 == s1 && ent.z < ent.y)) ? ent.z : ent.y;
        if (win != ent.y) {
            out_idx[ent.x] = (float)win;
            const float4* src = (const float4*)(w + (size_t)win * D_MODEL);
            float4* dst = (float4*)(out_q + (size_t)ent.x * D_MODEL);
            for (int c = 0; c < 128; ++c) dst[c] = src[c];
        }
    }
}

// ---------------- exact full scan, (row x K/4) work items + packed atomicMin ----------------
__global__ __launch_bounds__(256) void fullscan_part(
    const float* __restrict__ z, const float* __restrict__ w,
    const float* __restrict__ wsq, const int* __restrict__ listB,
    const int* __restrict__ counterB, u64* __restrict__ slots) {
    __shared__ float zs[D_MODEL];
    __shared__ u64 red[4];
    int cB = *counterB; if (cB > CAPB) cB = CAPB;
    int items = cB * 4;
    const int lane = threadIdx.x & 63;
    const int wv   = threadIdx.x >> 6;
    for (int it = blockIdx.x; it < items; it += gridDim.x) {
        int p = it >> 2, q = it & 3;
        int row = listB[p];
        __syncthreads();
        for (int c = threadIdx.x; c < D_MODEL; c += 256) zs[c] = z[(size_t)row * D_MODEL + c];
        __syncthreads();
        int kb = q * 1024 + threadIdx.x * 4;
        const float* wr = w + (size_t)kb * D_MODEL;
        float acc[4] = {0.f, 0.f, 0.f, 0.f};
        for (int c = 0; c < 128; ++c) {
            float4 zv = ((const float4*)zs)[c];
            #pragma unroll
            for (int r = 0; r < 4; ++r) {
                float4 wvv = ((const float4*)(wr + (size_t)r * D_MODEL))[c];
                acc[r] = fmaf(zv.x, wvv.x, acc[r]); acc[r] = fmaf(zv.y, wvv.y, acc[r]);
                acc[r] = fmaf(zv.z, wvv.z, acc[r]); acc[r] = fmaf(zv.w, wvv.w, acc[r]);
            }
        }
        float bv = 3.4e38f; int bi = 0;
        #pragma unroll
        for (int r = 0; r < 4; ++r) {
            float s = fmaf(-2.f, acc[r], wsq[kb + r]);
            if (s < bv) { bv = s; bi = kb + r; }
        }
        u64 key = ((u64)ordf(bv) << 32) | (u32)bi;
        #pragma unroll
        for (int off = 32; off; off >>= 1) {
            u64 o = __shfl_xor(key, off);
            if (o < key) key = o;
        }
        if (lane == 0) red[wv] = key;
        __syncthreads();
        if (threadIdx.x == 0) {
            u64 m = red[0];
            if (red[1] < m) m = red[1];
            if (red[2] < m) m = red[2];
            if (red[3] < m) m = red[3];
            atomicMin(&slots[p], m);
        }
    }
}

__global__ __launch_bounds__(256) void fullscan_final(
    const float* __restrict__ w, const int* __restrict__ listB,
    const int* __restrict__ counterB, const u64* __restrict__ slots,
    float* __restrict__ out_idx, float* __restrict__ out_q) {
    int cB = *counterB; if (cB > CAPB) cB = CAPB;
    const int wv = threadIdx.x >> 6, lane = threadIdx.x & 63;
    for (int p = blockIdx.x * 4 + wv; p < cB; p += gridDim.x * 4) {
        int row = listB[p];
        int win = (int)(u32)(slots[p] & 0xFFFFFFFFull);
        if (lane == 0) out_idx[row] = (float)win;
        const float4* src = (const float4*)(w + (size_t)win * D_MODEL);
        float4* dst = (float4*)(out_q + (size_t)row * D_MODEL);
        dst[lane] = src[lane];
        dst[lane + 64] = src[lane + 64];
    }
}

// ---------------- round-1 fp32 path (safety net if ws too small) ----------------
__global__ __launch_bounds__(256) void wsq_kernel(const float* __restrict__ w,
                                                  float* __restrict__ wsq) {
    int k    = blockIdx.x * 4 + (threadIdx.x >> 6);
    int lane = threadIdx.x & 63;
    const float4* row = (const float4*)(w + (size_t)k * D_MODEL);
    float s = 0.f;
    #pragma unroll
    for (int c = 0; c < 2; ++c) {
        float4 v = row[lane + 64 * c];
        s += v.x * v.x + v.y * v.y + v.z * v.z + v.w * v.w;
    }
    #pragma unroll
    for (int m = 32; m; m >>= 1) s += __shfl_xor(s, m, 64);
    if (lane == 0) wsq[k] = s;
}

__global__ __launch_bounds__(256) void vq_fp32(const float* __restrict__ z,
                                               const float* __restrict__ w,
                                               const float* __restrict__ wsq,
                                               float* __restrict__ out_idx,
                                               float* __restrict__ out_q) {
    __shared__ float zs[64][36];
    __shared__ float ws[128][36];
    __shared__ int   idx_s[64];
    const int tid = threadIdx.x;
    const int tx  = tid & 15;
    const int ty  = tid >> 4;
    const int m0  = blockIdx.x * 64;
    float minv[4]; int mini[4];
    #pragma unroll
    for (int i = 0; i < 4; ++i) { minv[i] = 3.4e38f; mini[i] = 0; }
    for (int k0 = 0; k0 < K_CB; k0 += 128) {
        float acc[4][8];
        #pragma unroll
        for (int i = 0; i < 4; ++i)
            #pragma unroll
            for (int j = 0; j < 8; ++j) acc[i][j] = 0.f;
        for (int d0 = 0; d0 < D_MODEL; d0 += 32) {
            __syncthreads();
            {
                int r = tid >> 3, c = tid & 7;
                #pragma unroll
                for (int it = 0; it < 2; ++it, r += 32)
                    *(float4*)&zs[r][c * 4] = ((const float4*)(z + (size_t)(m0 + r) * D_MODEL + d0))[c];
            }
            {
                int r = tid >> 3, c = tid & 7;
                #pragma unroll
                for (int it = 0; it < 4; ++it, r += 32)
                    *(float4*)&ws[r][c * 4] = ((const float4*)(w + (size_t)(k0 + r) * D_MODEL + d0))[c];
            }
            __syncthreads();
            #pragma unroll
            for (int d = 0; d < 32; d += 4) {
                float4 zv[4];
                #pragma unroll
                for (int i = 0; i < 4; ++i) zv[i] = *(const float4*)&zs[ty * 4 + i][d];
                float4 wv[8];
                #pragma unroll
                for (int j = 0; j < 8; ++j) wv[j] = *(const float4*)&ws[j * 16 + tx][d];
                #pragma unroll
                for (int i = 0; i < 4; ++i)
                    #pragma unroll
                    for (int j = 0; j < 8; ++j) {
                        acc[i][j] = fmaf(zv[i].x, wv[j].x, acc[i][j]);
                        acc[i][j] = fmaf(zv[i].y, wv[j].y, acc[i][j]);
                        acc[i][j] = fmaf(zv[i].z, wv[j].z, acc[i][j]);
                        acc[i][j] = fmaf(zv[i].w, wv[j].w, acc[i][j]);
                    }
            }
        }
        #pragma unroll
        for (int j = 0; j < 8; ++j) {
            int   k  = k0 + j * 16 + tx;
            float wq = wsq[k];
            #pragma unroll
            for (int i = 0; i < 4; ++i) {
                float s = fmaf(-2.f, acc[i][j], wq);
                if (s < minv[i]) { minv[i] = s; mini[i] = k; }
            }
        }
    }
    #pragma unroll
    for (int i = 0; i < 4; ++i) {
        float v = minv[i]; int ix = mini[i];
        #pragma unroll
        for (int m = 8; m; m >>= 1) {
            float ov = __shfl_xor(v, m, 16);
            int   oi = __shfl_xor(ix, m, 16);
            if (ov < v || (ov == v && oi < ix)) { v = ov; ix = oi; }
        }
        if (tx == 0) {
            int row = ty * 4 + i;
            out_idx[m0 + row] = (float)ix;
            idx_s[row] = ix;
        }
    }
    __syncthreads();
    const float4* w4 = (const float4*)w;
    float4*       o4 = (float4*)out_q;
    for (int t = tid; t < 64 * 128; t += 256) {
        int r = t >> 7, c = t & 127;
        o4[(size_t)(m0 + r) * 128 + c] = w4[(size_t)idx_s[r] * 128 + c];
    }
}

extern "C" void kernel_launch(void* const* d_in, const int* in_sizes, int n_in,
                              void* d_out, int out_size, void* d_ws, size_t ws_size,
                              hipStream_t stream) {
    const float* z = (const float*)d_in[0];
    const float* w = (const float*)d_in[1];
    float* out_idx = (float*)d_out;
    float* out_q   = (float*)d_out + N_ROWS;

    const size_t off_listA = 256;
    const size_t off_listB = off_listA + (size_t)CAPA * 16;
    const size_t off_slots = off_listB + (size_t)CAPB * 4;
    const size_t off_wsq   = off_slots + (size_t)CAPB * 8;
    const size_t off_wh    = off_wsq + (size_t)K_CB * 4;
    const size_t off_zh    = off_wh + (size_t)K_CB * D_MODEL * 2;
    const size_t NEED      = off_zh + (size_t)N_ROWS * D_MODEL * 2;

    if (ws_size >= NEED) {
        char* ws = (char*)d_ws;
        int*  counterA = (int*)ws;
        int*  counterB = (int*)(ws + 4);
        int4* listA    = (int4*)(ws + off_listA);
        int*  listB    = (int*)(ws + off_listB);
        u64*  slots    = (u64*)(ws + off_slots);
        float* wsq     = (float*)(ws + off_wsq);
        _Float16* wh   = (_Float16*)(ws + off_wh);
        _Float16* zh   = (_Float16*)(ws + off_zh);

        convert_z<<<(N_ROWS * D_MODEL) / (256 * 8), 256, 0, stream>>>(z, zh);
        convert_w<<<K_CB / 4, 256, 0, stream>>>(w, wh, wsq, counterA, counterB);
        gemm_argmin<<<N_ROWS / 64, 256, 0, stream>>>(zh, wh, w, wsq, out_idx, out_q,
                                                     listA, listB, slots,
                                                     counterA, counterB);
        verify_pairs<<<64, 256, 0, stream>>>(z, w, wsq, listA, counterA, out_idx, out_q);
        fullscan_part<<<512, 256, 0, stream>>>(z, w, wsq, listB, counterB, slots);
        fullscan_final<<<64, 256, 0, stream>>>(w, listB, counterB, slots, out_idx, out_q);
    } else {
        float* wsq = (float*)d_ws;
        wsq_kernel<<<K_CB / 4, 256, 0, stream>>>(w, wsq);
        vq_fp32<<<N_ROWS / 64, 256, 0, stream>>>(z, w, wsq, out_idx, out_q);
    }
}

// Round 9
// 770.606 us; speedup vs baseline: 1.1926x; 1.1926x over previous
//
#include <hip/hip_runtime.h>

#define N_ROWS  65536
#define K_CB    4096
#define D_MODEL 512
#define TAU     0.35f
#define CAPA    8192
#define CAPB    8192

typedef __attribute__((ext_vector_type(8))) _Float16 f16x8;
typedef __attribute__((ext_vector_type(4))) float f32x4;
typedef unsigned int        u32;
typedef unsigned long long  u64;

__device__ __forceinline__ void load_lds16(const void* g, void* l) {
    __builtin_amdgcn_global_load_lds(
        (const __attribute__((address_space(1))) u32*)g,
        (__attribute__((address_space(3))) u32*)l, 16, 0, 0);
}

__device__ __forceinline__ u32 ordf(float f) {
    u32 u = __float_as_uint(f);
    return (u >> 31) ? ~u : (u | 0x80000000u);
}

// ---------------- z -> fp16 ----------------
__global__ __launch_bounds__(256) void convert_z(const float* __restrict__ z,
                                                 _Float16* __restrict__ zh) {
    size_t i = ((size_t)blockIdx.x * 256 + threadIdx.x) * 8;
    float4 a = *(const float4*)(z + i);
    float4 b = *(const float4*)(z + i + 4);
    f16x8 o;
    o[0] = (_Float16)a.x; o[1] = (_Float16)a.y; o[2] = (_Float16)a.z; o[3] = (_Float16)a.w;
    o[4] = (_Float16)b.x; o[5] = (_Float16)b.y; o[6] = (_Float16)b.z; o[7] = (_Float16)b.w;
    *(f16x8*)(zh + i) = o;
}

// ---------------- w -> fp16 + wsq (fp32, validated chain) + zero counters ----------------
__global__ __launch_bounds__(256) void convert_w(const float* __restrict__ w,
                                                 _Float16* __restrict__ wh,
                                                 float* __restrict__ wsq,
                                                 int* __restrict__ counterA,
                                                 int* __restrict__ counterB) {
    if (blockIdx.x == 0 && threadIdx.x == 0) { *counterA = 0; *counterB = 0; }
    int k    = blockIdx.x * 4 + (threadIdx.x >> 6);
    int lane = threadIdx.x & 63;
    const float4* row = (const float4*)(w + (size_t)k * D_MODEL);
    float s = 0.f;
    #pragma unroll
    for (int c = 0; c < 2; ++c) {
        float4 v = row[lane + 64 * c];
        s += v.x * v.x + v.y * v.y + v.z * v.z + v.w * v.w;
        _Float16* o = wh + (size_t)k * D_MODEL + (lane + 64 * c) * 4;
        o[0] = (_Float16)v.x; o[1] = (_Float16)v.y; o[2] = (_Float16)v.z; o[3] = (_Float16)v.w;
    }
    #pragma unroll
    for (int m = 32; m; m >>= 1) s += __shfl_xor(s, m, 64);
    if (lane == 0) wsq[k] = s;
}

// ---------------- fused fp16-MFMA GEMM + top-3 argmin + classify + gather ----------------
// EXACT verified 638us structure: BM=64, 4 waves x (16 rows x 128 cols), BK=64,
// double-buffered LDS, flattened 256-chunk pipeline, counted vmcnt(6) + raw barriers.
// Only change vs that baseline: bijective XCD-aware block swizzle (locality only).
__global__ __launch_bounds__(256, 3) void gemm_argmin(
    const _Float16* __restrict__ zh, const _Float16* __restrict__ wh,
    const float* __restrict__ w, const float* __restrict__ wsq,
    float* __restrict__ out_idx, float* __restrict__ out_q,
    int4* __restrict__ listA, int* __restrict__ listB, u64* __restrict__ slots,
    int* __restrict__ counterA, int* __restrict__ counterB) {
    __shared__ _Float16 As[2][64 * 64];     // 2 x 8KB
    __shared__ _Float16 Bs[2][128 * 64];    // 2 x 16KB
    __shared__ int idx_s[64];

    const int tid  = threadIdx.x;
    const int lane = tid & 63;
    const int wv   = tid >> 6;
    // XCD-aware bijective swizzle: nwg=1024, 8 XCDs, q=128 chunks each
    const int bid  = blockIdx.x;
    const int swz  = (bid & 7) * 128 + (bid >> 3);
    const int m0   = swz * 64;
    const int l15  = lane & 15;
    const int g    = lane >> 4;

    const int srow = lane >> 3;            // row within an 8-row / 1KB chunk
    const int scol = (lane & 7) ^ srow;    // pre-swizzled source 16B-column

    float v1[4], v2[4], v3[4]; int i1[4], i2[4];
    #pragma unroll
    for (int i = 0; i < 4; ++i) { v1[i] = 3.4e38f; v2[i] = 3.4e38f; v3[i] = 3.4e38f; i1[i] = 0; i2[i] = 0; }

    // stage chunk (kts, d0s) into buffer b: 6 global_load_lds per wave
    auto STAGE = [&](int kts, int d0s, int b) {
        const int chA = wv << 1;                       // 2 A-chunks per wave
        const _Float16* as = zh + (size_t)(m0 + (chA << 3) + srow) * D_MODEL + d0s + scol * 8;
        load_lds16(as,                      &As[b][chA << 9]);
        load_lds16(as + (size_t)8 * D_MODEL, &As[b][(chA + 1) << 9]);
        const int chB = wv << 2;                       // 4 B-chunks per wave
        const _Float16* bs = wh + (size_t)(kts * 128 + (chB << 3) + srow) * D_MODEL + d0s + scol * 8;
        #pragma unroll
        for (int q = 0; q < 4; ++q)
            load_lds16(bs + (size_t)(q * 8) * D_MODEL, &Bs[b][(chB + q) << 9]);
    };

    STAGE(0, 0, 0);                                    // prologue: chunk 0 -> buf 0

    for (int kt = 0; kt < 32; ++kt) {
        f32x4 acc[8];
        float wq[8];
        #pragma unroll
        for (int dc = 0; dc < 8; ++dc) {
            const int cur = dc & 1;
            // ---- issue next chunk's stage (skip only after the very last chunk)
            if (dc < 7) {
                STAGE(kt, (dc + 1) << 6, cur ^ 1);
                asm volatile("s_waitcnt vmcnt(6)" ::: "memory");
            } else if (kt < 31) {
                STAGE(kt + 1, 0, cur ^ 1);
                asm volatile("s_waitcnt vmcnt(6)" ::: "memory");
            } else {
                asm volatile("s_waitcnt vmcnt(0)" ::: "memory");
            }
            __builtin_amdgcn_s_barrier();              // current chunk visible to all waves
            __builtin_amdgcn_sched_barrier(0);

            if (dc == 0) {
                #pragma unroll
                for (int n = 0; n < 8; ++n) {
                    acc[n] = (f32x4){0.f, 0.f, 0.f, 0.f};
                    wq[n] = wsq[(kt << 7) + (n << 4) + l15];
                }
            }

            // ---- compute: wave tile 16 rows x 128 cols, 16 MFMA
            #pragma unroll
            for (int h = 0; h < 2; ++h) {
                const int colq = (h << 2) + g;         // 16B-col unit (0..7)
                const int ar = (wv << 4) + l15;
                f16x8 af = *(const f16x8*)&As[cur][(ar << 6) + ((colq ^ (ar & 7)) << 3)];
                #pragma unroll
                for (int n = 0; n < 8; ++n) {
                    const int br = (n << 4) + l15;
                    f16x8 bv = *(const f16x8*)&Bs[cur][(br << 6) + ((colq ^ (br & 7)) << 3)];
                    acc[n] = __builtin_amdgcn_mfma_f32_16x16x32_f16(af, bv, acc[n], 0, 0, 0);
                }
            }

            // ---- kt epilogue: registers only (wq preloaded)
            if (dc == 7) {
                #pragma unroll
                for (int n = 0; n < 8; ++n) {
                    int k = (kt << 7) + (n << 4) + l15;
                    #pragma unroll
                    for (int r = 0; r < 4; ++r) {
                        float s = fmaf(-2.f, acc[n][r], wq[n]);
                        if (s < v3[r]) {
                            if (s < v1[r]) {
                                v3[r] = v2[r]; v2[r] = v1[r]; i2[r] = i1[r];
                                v1[r] = s; i1[r] = k;
                            } else if (s < v2[r]) {
                                v3[r] = v2[r]; v2[r] = s; i2[r] = k;
                            } else v3[r] = s;
                        }
                    }
                }
            }
            __builtin_amdgcn_sched_barrier(0);
            __builtin_amdgcn_s_barrier();              // all waves done reading buf[cur]
        }
    }

    // merge sorted-3 lists across the 16 column-lanes (lex on (value, idx))
    #pragma unroll
    for (int rs = 0; rs < 4; ++rs) {
        float a1 = v1[rs], a2 = v2[rs], a3 = v3[rs];
        int   j1 = i1[rs], j2 = i2[rs];
        #pragma unroll
        for (int off = 1; off < 16; off <<= 1) {
            float b1 = __shfl_xor(a1, off);
            float b2 = __shfl_xor(a2, off);
            float b3 = __shfl_xor(a3, off);
            int   k1 = __shfl_xor(j1, off);
            int   k2 = __shfl_xor(j2, off);
            bool l1 = (b1 < a1) || (b1 == a1 && k1 < j1);
            bool l2 = (b1 < a2) || (b1 == a2 && k1 < j2);
            bool l3 = (b1 < a3);
            if (l1)      { a3 = a2; a2 = a1; j2 = j1; a1 = b1; j1 = k1; }
            else if (l2) { a3 = a2; a2 = b1; j2 = k1; }
            else if (l3) { a3 = b1; }
            bool m2 = (b2 < a2) || (b2 == a2 && k2 < j2);
            bool m3 = (b2 < a3);
            if (m2)      { a3 = a2; a2 = b2; j2 = k2; }
            else if (m3) { a3 = b2; }
            a3 = fminf(a3, b3);
        }
        if (l15 == 0) {
            int rl = (wv << 4) + (g << 2) + rs;
            int row = m0 + rl;
            out_idx[row] = (float)j1;
            idx_s[rl] = j1;
            float lim = a1 + TAU;
            if (a3 <= lim) {                       // >=3 candidates: full exact scan
                int p = atomicAdd(counterB, 1);
                if (p < CAPB) { listB[p] = row; slots[p] = ~0ull; }
            } else if (a2 <= lim) {                // exactly 2 candidates: pair verify
                int p = atomicAdd(counterA, 1);
                if (p < CAPA) listA[p] = make_int4(row, j1, j2, 0);
                else {
                    int q = atomicAdd(counterB, 1);
                    if (q < CAPB) { listB[q] = row; slots[q] = ~0ull; }
                }
            }
        }
    }
    __syncthreads();

    // gather quantized rows with idx1 (fallback kernels overwrite their rows)
    const float4* w4 = (const float4*)w;
    float4* o4 = (float4*)out_q;
    for (int c = tid; c < 64 * 128; c += 256) {
        int r = c >> 7, cc = c & 127;
        o4[(size_t)(m0 + r) * 128 + cc] = w4[(size_t)idx_s[r] * 128 + cc];
    }
}

// ---------------- exact fp32 pair-verify (one lane per ambiguous row) ----------------
__global__ __launch_bounds__(256) void verify_pairs(
    const float* __restrict__ z, const float* __restrict__ w,
    const float* __restrict__ wsq, const int4* __restrict__ listA,
    const int* __restrict__ counterA,
    float* __restrict__ out_idx, float* __restrict__ out_q) {
    int cA = *counterA; if (cA > CAPA) cA = CAPA;
    for (int e = blockIdx.x * 256 + threadIdx.x; e < cA; e += gridDim.x * 256) {
        int4 ent = listA[e];
        const float4* zr = (const float4*)(z + (size_t)ent.x * D_MODEL);
        const float4* wa = (const float4*)(w + (size_t)ent.y * D_MODEL);
        const float4* wb = (const float4*)(w + (size_t)ent.z * D_MODEL);
        float d1 = 0.f, d2 = 0.f;
        #pragma unroll 8
        for (int c = 0; c < 128; ++c) {
            float4 zv = zr[c];
            float4 a  = wa[c];
            float4 b  = wb[c];
            d1 = fmaf(zv.x, a.x, d1); d1 = fmaf(zv.y, a.y, d1);
            d1 = fmaf(zv.z, a.z, d1); d1 = fmaf(zv.w, a.w, d1);
            d2 = fmaf(zv.x, b.x, d2); d2 = fmaf(zv.y, b.y, d2);
            d2 = fmaf(zv.z, b.z, d2); d2 = fmaf(zv.w, b.w, d2);
        }
        float s1 = fmaf(-2.f, d1, wsq[ent.y]);
        float s2 = fmaf(-2.f, d2, wsq[ent.z]);
        int win = (s2 < s1 || (s2 == s1 && ent.z < ent.y)) ? ent.z : ent.y;
        if (win != ent.y) {
            out_idx[ent.x] = (float)win;
            const float4* src = (const float4*)(w + (size_t)win * D_MODEL);
            float4* dst = (float4*)(out_q + (size_t)ent.x * D_MODEL);
            for (int c = 0; c < 128; ++c) dst[c] = src[c];
        }
    }
}

// ---------------- exact full scan, (row x K/4) work items + packed atomicMin ----------------
__global__ __launch_bounds__(256) void fullscan_part(
    const float* __restrict__ z, const float* __restrict__ w,
    const float* __restrict__ wsq, const int* __restrict__ listB,
    const int* __restrict__ counterB, u64* __restrict__ slots) {
    __shared__ float zs[D_MODEL];
    __shared__ u64 red[4];
    int cB = *counterB; if (cB > CAPB) cB = CAPB;
    int items = cB * 4;
    const int lane = threadIdx.x & 63;
    const int wv   = threadIdx.x >> 6;
    for (int it = blockIdx.x; it < items; it += gridDim.x) {
        int p = it >> 2, q = it & 3;
        int row = listB[p];
        __syncthreads();
        for (int c = threadIdx.x; c < D_MODEL; c += 256) zs[c] = z[(size_t)row * D_MODEL + c];
        __syncthreads();
        int kb = q * 1024 + threadIdx.x * 4;
        const float* wr = w + (size_t)kb * D_MODEL;
        float acc[4] = {0.f, 0.f, 0.f, 0.f};
        for (int c = 0; c < 128; ++c) {
            float4 zv = ((const float4*)zs)[c];
            #pragma unroll
            for (int r = 0; r < 4; ++r) {
                float4 wvv = ((const float4*)(wr + (size_t)r * D_MODEL))[c];
                acc[r] = fmaf(zv.x, wvv.x, acc[r]); acc[r] = fmaf(zv.y, wvv.y, acc[r]);
                acc[r] = fmaf(zv.z, wvv.z, acc[r]); acc[r] = fmaf(zv.w, wvv.w, acc[r]);
            }
        }
        float bv = 3.4e38f; int bi = 0;
        #pragma unroll
        for (int r = 0; r < 4; ++r) {
            float s = fmaf(-2.f, acc[r], wsq[kb + r]);
            if (s < bv) { bv = s; bi = kb + r; }
        }
        u64 key = ((u64)ordf(bv) << 32) | (u32)bi;
        #pragma unroll
        for (int off = 32; off; off >>= 1) {
            u64 o = __shfl_xor(key, off);
            if (o < key) key = o;
        }
        if (lane == 0) red[wv] = key;
        __syncthreads();
        if (threadIdx.x == 0) {
            u64 m = red[0];
            if (red[1] < m) m = red[1];
            if (red[2] < m) m = red[2];
            if (red[3] < m) m = red[3];
            atomicMin(&slots[p], m);
        }
    }
}

__global__ __launch_bounds__(256) void fullscan_final(
    const float* __restrict__ w, const int* __restrict__ listB,
    const int* __restrict__ counterB, const u64* __restrict__ slots,
    float* __restrict__ out_idx, float* __restrict__ out_q) {
    int cB = *counterB; if (cB > CAPB) cB = CAPB;
    const int wv = threadIdx.x >> 6, lane = threadIdx.x & 63;
    for (int p = blockIdx.x * 4 + wv; p < cB; p += gridDim.x * 4) {
        int row = listB[p];
        int win = (int)(u32)(slots[p] & 0xFFFFFFFFull);
        if (lane == 0) out_idx[row] = (float)win;
        const float4* src = (const float4*)(w + (size_t)win * D_MODEL);
        float4* dst = (float4*)(out_q + (size_t)row * D_MODEL);
        dst[lane] = src[lane];
        dst[lane + 64] = src[lane + 64];
    }
}

// ---------------- round-1 fp32 path (safety net if ws too small) ----------------
__global__ __launch_bounds__(256) void wsq_kernel(const float* __restrict__ w,
                                                  float* __restrict__ wsq) {
    int k    = blockIdx.x * 4 + (threadIdx.x >> 6);
    int lane = threadIdx.x & 63;
    const float4* row = (const float4*)(w + (size_t)k * D_MODEL);
    float s = 0.f;
    #pragma unroll
    for (int c = 0; c < 2; ++c) {
        float4 v = row[lane + 64 * c];
        s += v.x * v.x + v.y * v.y + v.z * v.z + v.w * v.w;
    }
    #pragma unroll
    for (int m = 32; m; m >>= 1) s += __shfl_xor(s, m, 64);
    if (lane == 0) wsq[k] = s;
}

__global__ __launch_bounds__(256) void vq_fp32(const float* __restrict__ z,
                                               const float* __restrict__ w,
                                               const float* __restrict__ wsq,
                                               float* __restrict__ out_idx,
                                               float* __restrict__ out_q) {
    __shared__ float zs[64][36];
    __shared__ float ws[128][36];
    __shared__ int   idx_s[64];
    const int tid = threadIdx.x;
    const int tx  = tid & 15;
    const int ty  = tid >> 4;
    const int m0  = blockIdx.x * 64;
    float minv[4]; int mini[4];
    #pragma unroll
    for (int i = 0; i < 4; ++i) { minv[i] = 3.4e38f; mini[i] = 0; }
    for (int k0 = 0; k0 < K_CB; k0 += 128) {
        float acc[4][8];
        #pragma unroll
        for (int i = 0; i < 4; ++i)
            #pragma unroll
            for (int j = 0; j < 8; ++j) acc[i][j] = 0.f;
        for (int d0 = 0; d0 < D_MODEL; d0 += 32) {
            __syncthreads();
            {
                int r = tid >> 3, c = tid & 7;
                #pragma unroll
                for (int it = 0; it < 2; ++it, r += 32)
                    *(float4*)&zs[r][c * 4] = ((const float4*)(z + (size_t)(m0 + r) * D_MODEL + d0))[c];
            }
            {
                int r = tid >> 3, c = tid & 7;
                #pragma unroll
                for (int it = 0; it < 4; ++it, r += 32)
                    *(float4*)&ws[r][c * 4] = ((const float4*)(w + (size_t)(k0 + r) * D_MODEL + d0))[c];
            }
            __syncthreads();
            #pragma unroll
            for (int d = 0; d < 32; d += 4) {
                float4 zv[4];
                #pragma unroll
                for (int i = 0; i < 4; ++i) zv[i] = *(const float4*)&zs[ty * 4 + i][d];
                float4 wv[8];
                #pragma unroll
                for (int j = 0; j < 8; ++j) wv[j] = *(const float4*)&ws[j * 16 + tx][d];
                #pragma unroll
                for (int i = 0; i < 4; ++i)
                    #pragma unroll
                    for (int j = 0; j < 8; ++j) {
                        acc[i][j] = fmaf(zv[i].x, wv[j].x, acc[i][j]);
                        acc[i][j] = fmaf(zv[i].y, wv[j].y, acc[i][j]);
                        acc[i][j] = fmaf(zv[i].z, wv[j].z, acc[i][j]);
                        acc[i][j] = fmaf(zv[i].w, wv[j].w, acc[i][j]);
                    }
            }
        }
        #pragma unroll
        for (int j = 0; j < 8; ++j) {
            int   k  = k0 + j * 16 + tx;
            float wq = wsq[k];
            #pragma unroll
            for (int i = 0; i < 4; ++i) {
                float s = fmaf(-2.f, acc[i][j], wq);
                if (s < minv[i]) { minv[i] = s; mini[i] = k; }
            }
        }
    }
    #pragma unroll
    for (int i = 0; i < 4; ++i) {
        float v = minv[i]; int ix = mini[i];
        #pragma unroll
        for (int m = 8; m; m >>= 1) {
            float ov = __shfl_xor(v, m, 16);
            int   oi = __shfl_xor(ix, m, 16);
            if (ov < v || (ov == v && oi < ix)) { v = ov; ix = oi; }
        }
        if (tx == 0) {
            int row = ty * 4 + i;
            out_idx[m0 + row] = (float)ix;
            idx_s[row] = ix;
        }
    }
    __syncthreads();
    const float4* w4 = (const float4*)w;
    float4*       o4 = (float4*)out_q;
    for (int t = tid; t < 64 * 128; t += 256) {
        int r = t >> 7, c = t & 127;
        o4[(size_t)(m0 + r) * 128 + c] = w4[(size_t)idx_s[r] * 128 + c];
    }
}

extern "C" void kernel_launch(void* const* d_in, const int* in_sizes, int n_in,
                              void* d_out, int out_size, void* d_ws, size_t ws_size,
                              hipStream_t stream) {
    const float* z = (const float*)d_in[0];
    const float* w = (const float*)d_in[1];
    float* out_idx = (float*)d_out;
    float* out_q   = (float*)d_out + N_ROWS;

    const size_t off_listA = 256;
    const size_t off_listB = off_listA + (size_t)CAPA * 16;
    const size_t off_slots = off_listB + (size_t)CAPB * 4;
    const size_t off_wsq   = off_slots + (size_t)CAPB * 8;
    const size_t off_wh    = off_wsq + (size_t)K_CB * 4;
    const size_t off_zh    = off_wh + (size_t)K_CB * D_MODEL * 2;
    const size_t NEED      = off_zh + (size_t)N_ROWS * D_MODEL * 2;

    if (ws_size >= NEED) {
        char* ws = (char*)d_ws;
        int*  counterA = (int*)ws;
        int*  counterB = (int*)(ws + 4);
        int4* listA    = (int4*)(ws + off_listA);
        int*  listB    = (int*)(ws + off_listB);
        u64*  slots    = (u64*)(ws + off_slots);
        float* wsq     = (float*)(ws + off_wsq);
        _Float16* wh   = (_Float16*)(ws + off_wh);
        _Float16* zh   = (_Float16*)(ws + off_zh);

        convert_z<<<(N_ROWS * D_MODEL) / (256 * 8), 256, 0, stream>>>(z, zh);
        convert_w<<<K_CB / 4, 256, 0, stream>>>(w, wh, wsq, counterA, counterB);
        gemm_argmin<<<N_ROWS / 64, 256, 0, stream>>>(zh, wh, w, wsq, out_idx, out_q,
                                                     listA, listB, slots,
                                                     counterA, counterB);
        verify_pairs<<<64, 256, 0, stream>>>(z, w, wsq, listA, counterA, out_idx, out_q);
        fullscan_part<<<512, 256, 0, stream>>>(z, w, wsq, listB, counterB, slots);
        fullscan_final<<<64, 256, 0, stream>>>(w, listB, counterB, slots, out_idx, out_q);
    } else {
        float* wsq = (float*)d_ws;
        wsq_kernel<<<K_CB / 4, 256, 0, stream>>>(w, wsq);
        vq_fp32<<<N_ROWS / 64, 256, 0, stream>>>(z, w, wsq, out_idx, out_q);
    }
}

// Round 10
// 741.449 us; speedup vs baseline: 1.2395x; 1.0393x over previous
//
#include <hip/hip_runtime.h>

#define N_ROWS  65536
#define K_CB    4096
#define D_MODEL 512
#define TAU     0.35f
#define CAPA    8192
#define CAPB    8192

typedef __attribute__((ext_vector_type(8))) _Float16 f16x8;
typedef __attribute__((ext_vector_type(4))) float f32x4;
typedef unsigned int        u32;
typedef unsigned long long  u64;

template<int N> struct ic { static constexpr int v = N; };

__device__ __forceinline__ void load_lds16(const void* g, void* l) {
    __builtin_amdgcn_global_load_lds(
        (const __attribute__((address_space(1))) u32*)g,
        (__attribute__((address_space(3))) u32*)l, 16, 0, 0);
}

__device__ __forceinline__ u32 ordf(float f) {
    u32 u = __float_as_uint(f);
    return (u >> 31) ? ~u : (u | 0x80000000u);
}

// ---------------- z -> fp16 ----------------
__global__ __launch_bounds__(256) void convert_z(const float* __restrict__ z,
                                                 _Float16* __restrict__ zh) {
    size_t i = ((size_t)blockIdx.x * 256 + threadIdx.x) * 8;
    float4 a = *(const float4*)(z + i);
    float4 b = *(const float4*)(z + i + 4);
    f16x8 o;
    o[0] = (_Float16)a.x; o[1] = (_Float16)a.y; o[2] = (_Float16)a.z; o[3] = (_Float16)a.w;
    o[4] = (_Float16)b.x; o[5] = (_Float16)b.y; o[6] = (_Float16)b.z; o[7] = (_Float16)b.w;
    *(f16x8*)(zh + i) = o;
}

// ---------------- w -> fp16 + wsq (fp32, validated chain) + zero counters ----------------
__global__ __launch_bounds__(256) void convert_w(const float* __restrict__ w,
                                                 _Float16* __restrict__ wh,
                                                 float* __restrict__ wsq,
                                                 int* __restrict__ counterA,
                                                 int* __restrict__ counterB) {
    if (blockIdx.x == 0 && threadIdx.x == 0) { *counterA = 0; *counterB = 0; }
    int k    = blockIdx.x * 4 + (threadIdx.x >> 6);
    int lane = threadIdx.x & 63;
    const float4* row = (const float4*)(w + (size_t)k * D_MODEL);
    float s = 0.f;
    #pragma unroll
    for (int c = 0; c < 2; ++c) {
        float4 v = row[lane + 64 * c];
        s += v.x * v.x + v.y * v.y + v.z * v.z + v.w * v.w;
        _Float16* o = wh + (size_t)k * D_MODEL + (lane + 64 * c) * 4;
        o[0] = (_Float16)v.x; o[1] = (_Float16)v.y; o[2] = (_Float16)v.z; o[3] = (_Float16)v.w;
    }
    #pragma unroll
    for (int m = 32; m; m >>= 1) s += __shfl_xor(s, m, 64);
    if (lane == 0) wsq[k] = s;
}

// ---------------- fused fp16-MFMA GEMM + top-3 argmin + classify + gather ----------------
// Verified r4/r9 wave geometry (BM=64, 4 waves x 16x128, BK=64, VGPR 76) with a
// deeper schedule: TRIPLE-buffered LDS, 2-chunk prefetch, ONE barrier per chunk.
// Body of chunk c: vmcnt(6) [c's loads oldest; c+1 in flight] -> barrier
// [all waves' c-loads landed + all finished compute c-1 -> safe to overwrite
// buf[(c+2)%3], last read at c-1] -> STAGE(c+2) -> compute c.
__global__ __launch_bounds__(256, 3) void gemm_argmin(
    const _Float16* __restrict__ zh, const _Float16* __restrict__ wh,
    const float* __restrict__ w, const float* __restrict__ wsq,
    float* __restrict__ out_idx, float* __restrict__ out_q,
    int4* __restrict__ listA, int* __restrict__ listB, u64* __restrict__ slots,
    int* __restrict__ counterA, int* __restrict__ counterB) {
    __shared__ _Float16 As[3][64 * 64];     // 3 x 8KB
    __shared__ _Float16 Bs[3][128 * 64];    // 3 x 16KB  (72KB total -> 2 blocks/CU)
    __shared__ int idx_s[64];

    const int tid  = threadIdx.x;
    const int lane = tid & 63;
    const int wv   = tid >> 6;
    // XCD-aware bijective swizzle: nwg=1024, 8 XCDs, 128 chunks each
    const int bid  = blockIdx.x;
    const int swz  = (bid & 7) * 128 + (bid >> 3);
    const int m0   = swz * 64;
    const int l15  = lane & 15;
    const int g    = lane >> 4;

    const int srow = lane >> 3;            // row within an 8-row / 1KB chunk
    const int scol = (lane & 7) ^ srow;    // pre-swizzled source 16B-column

    float v1[4], v2[4], v3[4]; int i1[4], i2[4];
    #pragma unroll
    for (int i = 0; i < 4; ++i) { v1[i] = 3.4e38f; v2[i] = 3.4e38f; v3[i] = 3.4e38f; i1[i] = 0; i2[i] = 0; }

    // stage chunk (kts, d0s) into buffer b: 6 global_load_lds per wave
    auto STAGE = [&](int kts, int d0s, int b) {
        const int chA = wv << 1;                       // 2 A-chunks per wave
        const _Float16* as = zh + (size_t)(m0 + (chA << 3) + srow) * D_MODEL + d0s + scol * 8;
        load_lds16(as,                      &As[b][chA << 9]);
        load_lds16(as + (size_t)8 * D_MODEL, &As[b][(chA + 1) << 9]);
        const int chB = wv << 2;                       // 4 B-chunks per wave
        const _Float16* bs = wh + (size_t)(kts * 128 + (chB << 3) + srow) * D_MODEL + d0s + scol * 8;
        #pragma unroll
        for (int q = 0; q < 4; ++q)
            load_lds16(bs + (size_t)(q * 8) * D_MODEL, &Bs[b][(chB + q) << 9]);
    };

    STAGE(0, 0, 0);                                    // prologue: chunk 0 -> buf 0
    STAGE(0, 64, 1);                                   //           chunk 1 -> buf 1

    // one kt-tile (8 chunks); P = buffer phase of chunk kt*8, compile-time
    auto KT = [&](int kt, auto pc) {
        constexpr int P = decltype(pc)::v;
        f32x4 acc[8];
        float wq[8];
        #pragma unroll
        for (int dc = 0; dc < 8; ++dc) {
            const int cur = (P + dc) % 3;
            const int nxt = (P + dc + 2) % 3;
            // 1. wait: chunk c's 6 loads are the oldest; keep c+1's 6 in flight
            if (kt == 31 && dc == 7) { asm volatile("s_waitcnt vmcnt(0)" ::: "memory"); }
            else                     { asm volatile("s_waitcnt vmcnt(6)" ::: "memory"); }
            // 2. barrier: all waves' c-loads landed; all finished compute c-1
            __builtin_amdgcn_s_barrier();
            __builtin_amdgcn_sched_barrier(0);
            // 3. stage chunk c+2 (skip for the last two chunks of the kernel)
            if (dc < 6)        STAGE(kt, (dc + 2) << 6, nxt);
            else if (kt < 31)  STAGE(kt + 1, (dc - 6) << 6, nxt);

            if (dc == 0) {
                #pragma unroll
                for (int n = 0; n < 8; ++n) {
                    acc[n] = (f32x4){0.f, 0.f, 0.f, 0.f};
                    wq[n] = wsq[(kt << 7) + (n << 4) + l15];
                }
            }

            // 4. compute: wave tile 16 rows x 128 cols, 16 MFMA
            #pragma unroll
            for (int h = 0; h < 2; ++h) {
                const int colq = (h << 2) + g;         // 16B-col unit (0..7)
                const int ar = (wv << 4) + l15;
                f16x8 af = *(const f16x8*)&As[cur][(ar << 6) + ((colq ^ (ar & 7)) << 3)];
                #pragma unroll
                for (int n = 0; n < 8; ++n) {
                    const int br = (n << 4) + l15;
                    f16x8 bv = *(const f16x8*)&Bs[cur][(br << 6) + ((colq ^ (br & 7)) << 3)];
                    acc[n] = __builtin_amdgcn_mfma_f32_16x16x32_f16(af, bv, acc[n], 0, 0, 0);
                }
            }

            // 5. kt epilogue: registers only (wq preloaded)
            if (dc == 7) {
                #pragma unroll
                for (int n = 0; n < 8; ++n) {
                    int k = (kt << 7) + (n << 4) + l15;
                    #pragma unroll
                    for (int r = 0; r < 4; ++r) {
                        float s = fmaf(-2.f, acc[n][r], wq[n]);
                        if (s < v3[r]) {
                            if (s < v1[r]) {
                                v3[r] = v2[r]; v2[r] = v1[r]; i2[r] = i1[r];
                                v1[r] = s; i1[r] = k;
                            } else if (s < v2[r]) {
                                v3[r] = v2[r]; v2[r] = s; i2[r] = k;
                            } else v3[r] = s;
                        }
                    }
                }
            }
            __builtin_amdgcn_sched_barrier(0);
        }
    };

    // phase of chunk kt*8 = (2*kt) % 3: pattern 0,2,1 repeating
    for (int ktg = 0; ktg < 30; ktg += 3) {
        KT(ktg,     ic<0>{});
        KT(ktg + 1, ic<2>{});
        KT(ktg + 2, ic<1>{});
    }
    KT(30, ic<0>{});
    KT(31, ic<2>{});

    // merge sorted-3 lists across the 16 column-lanes (lex on (value, idx))
    #pragma unroll
    for (int rs = 0; rs < 4; ++rs) {
        float a1 = v1[rs], a2 = v2[rs], a3 = v3[rs];
        int   j1 = i1[rs], j2 = i2[rs];
        #pragma unroll
        for (int off = 1; off < 16; off <<= 1) {
            float b1 = __shfl_xor(a1, off);
            float b2 = __shfl_xor(a2, off);
            float b3 = __shfl_xor(a3, off);
            int   k1 = __shfl_xor(j1, off);
            int   k2 = __shfl_xor(j2, off);
            bool l1 = (b1 < a1) || (b1 == a1 && k1 < j1);
            bool l2 = (b1 < a2) || (b1 == a2 && k1 < j2);
            bool l3 = (b1 < a3);
            if (l1)      { a3 = a2; a2 = a1; j2 = j1; a1 = b1; j1 = k1; }
            else if (l2) { a3 = a2; a2 = b1; j2 = k1; }
            else if (l3) { a3 = b1; }
            bool m2 = (b2 < a2) || (b2 == a2 && k2 < j2);
            bool m3 = (b2 < a3);
            if (m2)      { a3 = a2; a2 = b2; j2 = k2; }
            else if (m3) { a3 = b2; }
            a3 = fminf(a3, b3);
        }
        if (l15 == 0) {
            int rl = (wv << 4) + (g << 2) + rs;
            int row = m0 + rl;
            out_idx[row] = (float)j1;
            idx_s[rl] = j1;
            float lim = a1 + TAU;
            if (a3 <= lim) {                       // >=3 candidates: full exact scan
                int p = atomicAdd(counterB, 1);
                if (p < CAPB) { listB[p] = row; slots[p] = ~0ull; }
            } else if (a2 <= lim) {                // exactly 2 candidates: pair verify
                int p = atomicAdd(counterA, 1);
                if (p < CAPA) listA[p] = make_int4(row, j1, j2, 0);
                else {
                    int q = atomicAdd(counterB, 1);
                    if (q < CAPB) { listB[q] = row; slots[q] = ~0ull; }
                }
            }
        }
    }
    __syncthreads();

    // gather quantized rows with idx1 (fallback kernels overwrite their rows)
    const float4* w4 = (const float4*)w;
    float4* o4 = (float4*)out_q;
    for (int c = tid; c < 64 * 128; c += 256) {
        int r = c >> 7, cc = c & 127;
        o4[(size_t)(m0 + r) * 128 + cc] = w4[(size_t)idx_s[r] * 128 + cc];
    }
}

// ---------------- exact fp32 pair-verify (one lane per ambiguous row) ----------------
__global__ __launch_bounds__(256) void verify_pairs(
    const float* __restrict__ z, const float* __restrict__ w,
    const float* __restrict__ wsq, const int4* __restrict__ listA,
    const int* __restrict__ counterA,
    float* __restrict__ out_idx, float* __restrict__ out_q) {
    int cA = *counterA; if (cA > CAPA) cA = CAPA;
    for (int e = blockIdx.x * 256 + threadIdx.x; e < cA; e += gridDim.x * 256) {
        int4 ent = listA[e];
        const float4* zr = (const float4*)(z + (size_t)ent.x * D_MODEL);
        const float4* wa = (const float4*)(w + (size_t)ent.y * D_MODEL);
        const float4* wb = (const float4*)(w + (size_t)ent.z * D_MODEL);
        float d1 = 0.f, d2 = 0.f;
        #pragma unroll 8
        for (int c = 0; c < 128; ++c) {
            float4 zv = zr[c];
            float4 a  = wa[c];
            float4 b  = wb[c];
            d1 = fmaf(zv.x, a.x, d1); d1 = fmaf(zv.y, a.y, d1);
            d1 = fmaf(zv.z, a.z, d1); d1 = fmaf(zv.w, a.w, d1);
            d2 = fmaf(zv.x, b.x, d2); d2 = fmaf(zv.y, b.y, d2);
            d2 = fmaf(zv.z, b.z, d2); d2 = fmaf(zv.w, b.w, d2);
        }
        float s1 = fmaf(-2.f, d1, wsq[ent.y]);
        float s2 = fmaf(-2.f, d2, wsq[ent.z]);
        int win = (s2 < s1 || (s2 == s1 && ent.z < ent.y)) ? ent.z : ent.y;
        if (win != ent.y) {
            out_idx[ent.x] = (float)win;
            const float4* src = (const float4*)(w + (size_t)win * D_MODEL);
            float4* dst = (float4*)(out_q + (size_t)ent.x * D_MODEL);
            for (int c = 0; c < 128; ++c) dst[c] = src[c];
        }
    }
}

// ---------------- exact full scan, (row x K/4) work items + packed atomicMin ----------------
__global__ __launch_bounds__(256) void fullscan_part(
    const float* __restrict__ z, const float* __restrict__ w,
    const float* __restrict__ wsq, const int* __restrict__ listB,
    const int* __restrict__ counterB, u64* __restrict__ slots) {
    __shared__ float zs[D_MODEL];
    __shared__ u64 red[4];
    int cB = *counterB; if (cB > CAPB) cB = CAPB;
    int items = cB * 4;
    const int lane = threadIdx.x & 63;
    const int wv   = threadIdx.x >> 6;
    for (int it = blockIdx.x; it < items; it += gridDim.x) {
        int p = it >> 2, q = it & 3;
        int row = listB[p];
        __syncthreads();
        for (int c = threadIdx.x; c < D_MODEL; c += 256) zs[c] = z[(size_t)row * D_MODEL + c];
        __syncthreads();
        int kb = q * 1024 + threadIdx.x * 4;
        const float* wr = w + (size_t)kb * D_MODEL;
        float acc[4] = {0.f, 0.f, 0.f, 0.f};
        for (int c = 0; c < 128; ++c) {
            float4 zv = ((const float4*)zs)[c];
            #pragma unroll
            for (int r = 0; r < 4; ++r) {
                float4 wvv = ((const float4*)(wr + (size_t)r * D_MODEL))[c];
                acc[r] = fmaf(zv.x, wvv.x, acc[r]); acc[r] = fmaf(zv.y, wvv.y, acc[r]);
                acc[r] = fmaf(zv.z, wvv.z, acc[r]); acc[r] = fmaf(zv.w, wvv.w, acc[r]);
            }
        }
        float bv = 3.4e38f; int bi = 0;
        #pragma unroll
        for (int r = 0; r < 4; ++r) {
            float s = fmaf(-2.f, acc[r], wsq[kb + r]);
            if (s < bv) { bv = s; bi = kb + r; }
        }
        u64 key = ((u64)ordf(bv) << 32) | (u32)bi;
        #pragma unroll
        for (int off = 32; off; off >>= 1) {
            u64 o = __shfl_xor(key, off);
            if (o < key) key = o;
        }
        if (lane == 0) red[wv] = key;
        __syncthreads();
        if (threadIdx.x == 0) {
            u64 m = red[0];
            if (red[1] < m) m = red[1];
            if (red[2] < m) m = red[2];
            if (red[3] < m) m = red[3];
            atomicMin(&slots[p], m);
        }
    }
}

__global__ __launch_bounds__(256) void fullscan_final(
    const float* __restrict__ w, const int* __restrict__ listB,
    const int* __restrict__ counterB, const u64* __restrict__ slots,
    float* __restrict__ out_idx, float* __restrict__ out_q) {
    int cB = *counterB; if (cB > CAPB) cB = CAPB;
    const int wv = threadIdx.x >> 6, lane = threadIdx.x & 63;
    for (int p = blockIdx.x * 4 + wv; p < cB; p += gridDim.x * 4) {
        int row = listB[p];
        int win = (int)(u32)(slots[p] & 0xFFFFFFFFull);
        if (lane == 0) out_idx[row] = (float)win;
        const float4* src = (const float4*)(w + (size_t)win * D_MODEL);
        float4* dst = (float4*)(out_q + (size_t)row * D_MODEL);
        dst[lane] = src[lane];
        dst[lane + 64] = src[lane + 64];
    }
}

// ---------------- round-1 fp32 path (safety net if ws too small) ----------------
__global__ __launch_bounds__(256) void wsq_kernel(const float* __restrict__ w,
                                                  float* __restrict__ wsq) {
    int k    = blockIdx.x * 4 + (threadIdx.x >> 6);
    int lane = threadIdx.x & 63;
    const float4* row = (const float4*)(w + (size_t)k * D_MODEL);
    float s = 0.f;
    #pragma unroll
    for (int c = 0; c < 2; ++c) {
        float4 v = row[lane + 64 * c];
        s += v.x * v.x + v.y * v.y + v.z * v.z + v.w * v.w;
    }
    #pragma unroll
    for (int m = 32; m; m >>= 1) s += __shfl_xor(s, m, 64);
    if (lane == 0) wsq[k] = s;
}

__global__ __launch_bounds__(256) void vq_fp32(const float* __restrict__ z,
                                               const float* __restrict__ w,
                                               const float* __restrict__ wsq,
                                               float* __restrict__ out_idx,
                                               float* __restrict__ out_q) {
    __shared__ float zs[64][36];
    __shared__ float ws[128][36];
    __shared__ int   idx_s[64];
    const int tid = threadIdx.x;
    const int tx  = tid & 15;
    const int ty  = tid >> 4;
    const int m0  = blockIdx.x * 64;
    float minv[4]; int mini[4];
    #pragma unroll
    for (int i = 0; i < 4; ++i) { minv[i] = 3.4e38f; mini[i] = 0; }
    for (int k0 = 0; k0 < K_CB; k0 += 128) {
        float acc[4][8];
        #pragma unroll
        for (int i = 0; i < 4; ++i)
            #pragma unroll
            for (int j = 0; j < 8; ++j) acc[i][j] = 0.f;
        for (int d0 = 0; d0 < D_MODEL; d0 += 32) {
            __syncthreads();
            {
                int r = tid >> 3, c = tid & 7;
                #pragma unroll
                for (int it = 0; it < 2; ++it, r += 32)
                    *(float4*)&zs[r][c * 4] = ((const float4*)(z + (size_t)(m0 + r) * D_MODEL + d0))[c];
            }
            {
                int r = tid >> 3, c = tid & 7;
                #pragma unroll
                for (int it = 0; it < 4; ++it, r += 32)
                    *(float4*)&ws[r][c * 4] = ((const float4*)(w + (size_t)(k0 + r) * D_MODEL + d0))[c];
            }
            __syncthreads();
            #pragma unroll
            for (int d = 0; d < 32; d += 4) {
                float4 zv[4];
                #pragma unroll
                for (int i = 0; i < 4; ++i) zv[i] = *(const float4*)&zs[ty * 4 + i][d];
                float4 wv[8];
                #pragma unroll
                for (int j = 0; j < 8; ++j) wv[j] = *(const float4*)&ws[j * 16 + tx][d];
                #pragma unroll
                for (int i = 0; i < 4; ++i)
                    #pragma unroll
                    for (int j = 0; j < 8; ++j) {
                        acc[i][j] = fmaf(zv[i].x, wv[j].x, acc[i][j]);
                        acc[i][j] = fmaf(zv[i].y, wv[j].y, acc[i][j]);
                        acc[i][j] = fmaf(zv[i].z, wv[j].z, acc[i][j]);
                        acc[i][j] = fmaf(zv[i].w, wv[j].w, acc[i][j]);
                    }
            }
        }
        #pragma unroll
        for (int j = 0; j < 8; ++j) {
            int   k  = k0 + j * 16 + tx;
            float wq = wsq[k];
            #pragma unroll
            for (int i = 0; i < 4; ++i) {
                float s = fmaf(-2.f, acc[i][j], wq);
                if (s < minv[i]) { minv[i] = s; mini[i] = k; }
            }
        }
    }
    #pragma unroll
    for (int i = 0; i < 4; ++i) {
        float v = minv[i]; int ix = mini[i];
        #pragma unroll
        for (int m = 8; m; m >>= 1) {
            float ov = __shfl_xor(v, m, 16);
            int   oi = __shfl_xor(ix, m, 16);
            if (ov < v || (ov == v && oi < ix)) { v = ov; ix = oi; }
        }
        if (tx == 0) {
            int row = ty * 4 + i;
            out_idx[m0 + row] = (float)ix;
            idx_s[row] = ix;
        }
    }
    __syncthreads();
    const float4* w4 = (const float4*)w;
    float4*       o4 = (float4*)out_q;
    for (int t = tid; t < 64 * 128; t += 256) {
        int r = t >> 7, c = t & 127;
        o4[(size_t)(m0 + r) * 128 + c] = w4[(size_t)idx_s[r] * 128 + c];
    }
}

extern "C" void kernel_launch(void* const* d_in, const int* in_sizes, int n_in,
                              void* d_out, int out_size, void* d_ws, size_t ws_size,
                              hipStream_t stream) {
    const float* z = (const float*)d_in[0];
    const float* w = (const float*)d_in[1];
    float* out_idx = (float*)d_out;
    float* out_q   = (float*)d_out + N_ROWS;

    const size_t off_listA = 256;
    const size_t off_listB = off_listA + (size_t)CAPA * 16;
    const size_t off_slots = off_listB + (size_t)CAPB * 4;
    const size_t off_wsq   = off_slots + (size_t)CAPB * 8;
    const size_t off_wh    = off_wsq + (size_t)K_CB * 4;
    const size_t off_zh    = off_wh + (size_t)K_CB * D_MODEL * 2;
    const size_t NEED      = off_zh + (size_t)N_ROWS * D_MODEL * 2;

    if (ws_size >= NEED) {
        char* ws = (char*)d_ws;
        int*  counterA = (int*)ws;
        int*  counterB = (int*)(ws + 4);
        int4* listA    = (int4*)(ws + off_listA);
        int*  listB    = (int*)(ws + off_listB);
        u64*  slots    = (u64*)(ws + off_slots);
        float* wsq     = (float*)(ws + off_wsq);
        _Float16* wh   = (_Float16*)(ws + off_wh);
        _Float16* zh   = (_Float16*)(ws + off_zh);

        convert_z<<<(N_ROWS * D_MODEL) / (256 * 8), 256, 0, stream>>>(z, zh);
        convert_w<<<K_CB / 4, 256, 0, stream>>>(w, wh, wsq, counterA, counterB);
        gemm_argmin<<<N_ROWS / 64, 256, 0, stream>>>(zh, wh, w, wsq, out_idx, out_q,
                                                     listA, listB, slots,
                                                     counterA, counterB);
        verify_pairs<<<64, 256, 0, stream>>>(z, w, wsq, listA, counterA, out_idx, out_q);
        fullscan_part<<<512, 256, 0, stream>>>(z, w, wsq, listB, counterB, slots);
        fullscan_final<<<64, 256, 0, stream>>>(w, listB, counterB, slots, out_idx, out_q);
    } else {
        float* wsq = (float*)d_ws;
        wsq_kernel<<<K_CB / 4, 256, 0, stream>>>(w, wsq);
        vq_fp32<<<N_ROWS / 64, 256, 0, stream>>>(z, w, wsq, out_idx, out_q);
    }
}